// Round 3
// baseline (718.400 us; speedup 1.0000x reference)
//
#include <hip/hip_runtime.h>
#include <hip/hip_bf16.h>

#define T_SEQ 1024
#define BATCH 512
#define INPUT 64
#define HID   128

typedef __attribute__((ext_vector_type(8))) short bf16x8;
typedef __attribute__((ext_vector_type(4))) short s16x4;
typedef __attribute__((ext_vector_type(4))) float f32x4;
typedef __attribute__((ext_vector_type(2))) unsigned int u32x2;

#define MFMA __builtin_amdgcn_mfma_f32_16x16x32_bf16

__device__ __forceinline__ short f2bf(float f) {
    union { float f; unsigned u; } v; v.f = f;
    unsigned r = (v.u + 0x7FFFu + ((v.u >> 16) & 1u)) >> 16;
    return (short)r;
}

// packed RNE f32x2 -> bf16x2
__device__ __forceinline__ unsigned cvtpk_bf16(float lo, float hi) {
    unsigned r;
    asm("v_cvt_pk_bf16_f32 %0, %1, %2" : "=v"(r) : "v"(lo), "v"(hi));
    return r;
}

// tanh(x) = 1 - 2/(exp(2x)+1); inf-safe
__device__ __forceinline__ float fast_tanh(float s) {
    float e = __expf(2.0f * s);
    return 1.0f - 2.0f * __builtin_amdgcn_rcpf(e + 1.0f);
}

__device__ __forceinline__ float hsig(float v) {
    return __builtin_amdgcn_fmed3f(v * 0.16666666666666666f + 0.5f, 0.0f, 1.0f);
}

// Barrier draining ONLY lgkmcnt (LDS). Global x-prefetch loads stay in flight.
__device__ __forceinline__ void wg_barrier_lds() {
    asm volatile("s_waitcnt lgkmcnt(0)" ::: "memory");
    __builtin_amdgcn_s_barrier();
    asm volatile("" ::: "memory");
}

// ---------------- prep: f32 -> bf16 bulk convert ----------------
__global__ __launch_bounds__(256) void cvt_kernel(const float* __restrict__ in,
                                                  short* __restrict__ out, int n4) {
    int i = blockIdx.x * 256 + threadIdx.x;
    if (i >= n4) return;
    f32x4 v = ((const f32x4*)in)[i];
    s16x4 o;
    #pragma unroll
    for (int j = 0; j < 4; ++j) o[j] = f2bf(v[j]);
    ((s16x4*)out)[i] = o;
}

// ---------------- Stage 1: recurrence (4 waves, fat row ownership) ----------------
// 32 blocks x 256 threads (4 waves, 1/SIMD). Block: 16 batches.
// LDS-traffic model: reads = (#h-consumers) x 4KB. Rounds 0-2 had 8 consumers
// (32 b128 reads/step, ~640cyc LDS pipe = the bottleneck). Here: 4 waves, wave c
// owns hidden rows [32c,32c+32) for h-MFMA AND gate-MFMA AND x-MFMA, reusing one
// set of ds_read fragments -> 16 reads/step. Trans (tanh exp/rcp) stays spread:
// 16 trans insts/SIMD/step.
// Pipelining within each wave: gate(t-1) computed at step t (same frags as h(t),
// consumed next step); agg term for t-2 applied in the ds_read shadow of step t;
// accx(t+1) x-MFMAs also in the shadow; x prefetched 2 steps ahead.
template<bool PRE>
__global__ __launch_bounds__(256) void rnn_kernel(
    const float* __restrict__ xf_, const short* __restrict__ xb,
    const float* __restrict__ W_ih, const float* __restrict__ b_ih,
    const float* __restrict__ W_hh, const float* __restrict__ b_hh,
    const float* __restrict__ W_gate, const float* __restrict__ b_gate,
    float* __restrict__ agg_out)
{
    __shared__ __align__(16) short sh[2][16][136];  // pitch 136 shorts: even bank spread

    const int tid  = threadIdx.x;
    const int wave = tid >> 6, lane = tid & 63;
    const int q = lane >> 4, l15 = lane & 15;
    const int b0 = blockIdx.x * 16;
    const int R0 = 32 * wave, R1 = R0 + 16;

    // ---- one-time: weight A-frags (lane: W[row = Rt + l15][k = 32f + q*8 + j]) ----
    bf16x8 wih[2][2], whh[2][4], wgf[2][4];
    #pragma unroll
    for (int tile = 0; tile < 2; ++tile) {
        const int row = (tile ? R1 : R0) + l15;
        #pragma unroll
        for (int f = 0; f < 2; ++f) {
            const float* p = W_ih + row * INPUT + f * 32 + q * 8;
            bf16x8 v;
            #pragma unroll
            for (int j = 0; j < 8; ++j) v[j] = f2bf(p[j]);
            wih[tile][f] = v;
        }
        #pragma unroll
        for (int f = 0; f < 4; ++f) {
            const float* p = W_hh + row * HID + f * 32 + q * 8;
            bf16x8 v;
            #pragma unroll
            for (int j = 0; j < 8; ++j) v[j] = f2bf(p[j]);
            whh[tile][f] = v;
        }
        #pragma unroll
        for (int f = 0; f < 4; ++f) {
            const float* p = W_gate + row * HID + f * 32 + q * 8;
            bf16x8 v;
            #pragma unroll
            for (int j = 0; j < 8; ++j) v[j] = f2bf(p[j]);
            wgf[tile][f] = v;
        }
    }

    // ---- biases in C^T layout: row = Rt + q*4 + r ----
    f32x4 bias1[2], biasg[2], zero4;
    #pragma unroll
    for (int tile = 0; tile < 2; ++tile) {
        const int rbase = (tile ? R1 : R0) + q * 4;
        #pragma unroll
        for (int r = 0; r < 4; ++r) {
            bias1[tile][r] = b_ih[rbase + r] + b_hh[rbase + r];
            biasg[tile][r] = b_gate[rbase + r];
        }
    }
    #pragma unroll
    for (int r = 0; r < 4; ++r) zero4[r] = 0.0f;

    f32x4 agg0 = zero4, agg1 = zero4;
    f32x4 hp1_0 = zero4, hp1_1 = zero4;   // h(t-1) own values (f32, C^T layout)
    f32x4 hp2_0 = zero4, hp2_1 = zero4;   // h(t-2)
    f32x4 gat0 = zero4, gat1 = zero4;     // gate(t-2) results (C^T)
    f32x4 axA0, axA1, axB0, axB1;         // accx ping-pong (main vs shadow)
    bf16x8 xB0a, xB0b, xB1a, xB1b;        // x frag buffers (consumed 2 steps after load)

    const long lanebase = ((long)(b0 + l15) * T_SEQ) * INPUT + q * 8;
    const short* xb_lane = PRE ? (xb + lanebase) : nullptr;
    const float* xf_lane = PRE ? nullptr : (xf_ + lanebase);

    auto load_pair = [&](int tt, bf16x8& fa, bf16x8& fb) {
        if constexpr (PRE) {
            const short* p = xb_lane + (long)tt * INPUT;
            fa = *(const bf16x8*)p;
            fb = *(const bf16x8*)(p + 32);
        } else {
            const float* p = xf_lane + (long)tt * INPUT;
            f32x4 a0 = *(const f32x4*)p,        a1 = *(const f32x4*)(p + 4);
            f32x4 a2 = *(const f32x4*)(p + 32), a3 = *(const f32x4*)(p + 36);
            #pragma unroll
            for (int j = 0; j < 4; ++j) {
                fa[j] = f2bf(a0[j]); fa[4 + j] = f2bf(a1[j]);
                fb[j] = f2bf(a2[j]); fb[4 + j] = f2bf(a3[j]);
            }
        }
    };

    // step t: read h(t-1) from sh[(t-1)&1]; shadow {agg(t-2), accx(t+1), refill x};
    // h(t) + gate(t-1) MFMAs; tanh; pack+write sh[t&1]; barrier.
    auto step = [&](int t, f32x4& axM0, f32x4& axM1, f32x4& axS0, f32x4& axS1,
                    bf16x8& xfa, bf16x8& xfb) {
        const int rb = (t & 1) ^ 1, wb = t & 1;
        // 1. issue h(t-1) frag reads
        bf16x8 hf0 = *(const bf16x8*)&sh[rb][l15][q * 8];
        bf16x8 hf1 = *(const bf16x8*)&sh[rb][l15][32 + q * 8];
        bf16x8 hf2 = *(const bf16x8*)&sh[rb][l15][64 + q * 8];
        bf16x8 hf3 = *(const bf16x8*)&sh[rb][l15][96 + q * 8];
        // 2. shadow work (no LDS dependence): agg term for t-2
        #pragma unroll
        for (int r = 0; r < 4; ++r) {
            agg0[r] += hp2_0[r] * hsig(gat0[r]);
            agg1[r] += hp2_1[r] * hsig(gat1[r]);
        }
        //    accx(t+1) from x(t+1) (loaded 2 steps ago)
        axS0 = MFMA(wih[0][0], xfa, bias1[0], 0, 0, 0);
        axS1 = MFMA(wih[1][0], xfa, bias1[1], 0, 0, 0);
        axS0 = MFMA(wih[0][1], xfb, axS0, 0, 0, 0);
        axS1 = MFMA(wih[1][1], xfb, axS1, 0, 0, 0);
        //    refill this buffer with x(t+3) (clamped; harmless redundant tail loads)
        int tt = t + 3; if (tt > T_SEQ - 1) tt = T_SEQ - 1;
        load_pair(tt, xfa, xfb);
        // 3. h(t) = tanh(W_hh h(t-1) + accx(t)) : 2+2 split for dep latency
        f32x4 a0 = MFMA(whh[0][0], hf0, axM0, 0, 0, 0);
        f32x4 c0 = MFMA(whh[0][2], hf2, zero4, 0, 0, 0);
        f32x4 a1 = MFMA(whh[1][0], hf0, axM1, 0, 0, 0);
        f32x4 c1 = MFMA(whh[1][2], hf2, zero4, 0, 0, 0);
        a0 = MFMA(whh[0][1], hf1, a0, 0, 0, 0);
        c0 = MFMA(whh[0][3], hf3, c0, 0, 0, 0);
        a1 = MFMA(whh[1][1], hf1, a1, 0, 0, 0);
        c1 = MFMA(whh[1][3], hf3, c1, 0, 0, 0);
        // 4. gate(t-1): same frags, 4-chain (latency-free: consumed next step)
        gat0 = MFMA(wgf[0][0], hf0, biasg[0], 0, 0, 0);
        gat0 = MFMA(wgf[0][1], hf1, gat0, 0, 0, 0);
        gat0 = MFMA(wgf[0][2], hf2, gat0, 0, 0, 0);
        gat0 = MFMA(wgf[0][3], hf3, gat0, 0, 0, 0);
        gat1 = MFMA(wgf[1][0], hf0, biasg[1], 0, 0, 0);
        gat1 = MFMA(wgf[1][1], hf1, gat1, 0, 0, 0);
        gat1 = MFMA(wgf[1][2], hf2, gat1, 0, 0, 0);
        gat1 = MFMA(wgf[1][3], hf3, gat1, 0, 0, 0);
        // 5. activation + history shift
        hp2_0 = hp1_0; hp2_1 = hp1_1;
        hp1_0[0] = fast_tanh(a0[0] + c0[0]);
        hp1_0[1] = fast_tanh(a0[1] + c0[1]);
        hp1_0[2] = fast_tanh(a0[2] + c0[2]);
        hp1_0[3] = fast_tanh(a0[3] + c0[3]);
        hp1_1[0] = fast_tanh(a1[0] + c1[0]);
        hp1_1[1] = fast_tanh(a1[1] + c1[1]);
        hp1_1[2] = fast_tanh(a1[2] + c1[2]);
        hp1_1[3] = fast_tanh(a1[3] + c1[3]);
        u32x2 p0, p1;
        p0[0] = cvtpk_bf16(hp1_0[0], hp1_0[1]); p0[1] = cvtpk_bf16(hp1_0[2], hp1_0[3]);
        p1[0] = cvtpk_bf16(hp1_1[0], hp1_1[1]); p1[1] = cvtpk_bf16(hp1_1[2], hp1_1[3]);
        *(u32x2*)&sh[wb][l15][R0 + q * 4] = p0;
        *(u32x2*)&sh[wb][l15][R1 + q * 4] = p1;
        wg_barrier_lds();
    };

    // ---- prologue ----
    {
        bf16x8 ta, tb;
        load_pair(0, ta, tb);
        axA0 = MFMA(wih[0][0], ta, bias1[0], 0, 0, 0);
        axA1 = MFMA(wih[1][0], ta, bias1[1], 0, 0, 0);
        axA0 = MFMA(wih[0][1], tb, axA0, 0, 0, 0);
        axA1 = MFMA(wih[1][1], tb, axA1, 0, 0, 0);
        // h(0) = tanh(accx(0))
        hp1_0[0] = fast_tanh(axA0[0]); hp1_0[1] = fast_tanh(axA0[1]);
        hp1_0[2] = fast_tanh(axA0[2]); hp1_0[3] = fast_tanh(axA0[3]);
        hp1_1[0] = fast_tanh(axA1[0]); hp1_1[1] = fast_tanh(axA1[1]);
        hp1_1[2] = fast_tanh(axA1[2]); hp1_1[3] = fast_tanh(axA1[3]);
        u32x2 p0, p1;
        p0[0] = cvtpk_bf16(hp1_0[0], hp1_0[1]); p0[1] = cvtpk_bf16(hp1_0[2], hp1_0[3]);
        p1[0] = cvtpk_bf16(hp1_1[0], hp1_1[1]); p1[1] = cvtpk_bf16(hp1_1[2], hp1_1[3]);
        *(u32x2*)&sh[0][l15][R0 + q * 4] = p0;
        *(u32x2*)&sh[0][l15][R1 + q * 4] = p1;
        // accx(1)
        load_pair(1, ta, tb);
        axA0 = MFMA(wih[0][0], ta, bias1[0], 0, 0, 0);
        axA1 = MFMA(wih[1][0], ta, bias1[1], 0, 0, 0);
        axA0 = MFMA(wih[0][1], tb, axA0, 0, 0, 0);
        axA1 = MFMA(wih[1][1], tb, axA1, 0, 0, 0);
        // prefetch x(2), x(3)
        load_pair(2, xB0a, xB0b);
        load_pair(3, xB1a, xB1b);
        wg_barrier_lds();
    }

    // ---- main loop: t = 1..1022 in pairs, tail t = 1023 ----
    for (int i = 0; i < 511; ++i) {
        step(2 * i + 1, axA0, axA1, axB0, axB1, xB0a, xB0b);
        step(2 * i + 2, axB0, axB1, axA0, axA1, xB1a, xB1b);
    }
    step(1023, axA0, axA1, axB0, axB1, xB0a, xB0b);

    // ---- epilogue ----
    // t=1022 term: gat holds gate(1022), hp2 holds h(1022)
    #pragma unroll
    for (int r = 0; r < 4; ++r) {
        agg0[r] += hp2_0[r] * hsig(gat0[r]);
        agg1[r] += hp2_1[r] * hsig(gat1[r]);
    }
    // t=1023 term: read h(1023) from sh[1] (tail's barrier makes it visible)
    {
        bf16x8 hf0 = *(const bf16x8*)&sh[1][l15][q * 8];
        bf16x8 hf1 = *(const bf16x8*)&sh[1][l15][32 + q * 8];
        bf16x8 hf2 = *(const bf16x8*)&sh[1][l15][64 + q * 8];
        bf16x8 hf3 = *(const bf16x8*)&sh[1][l15][96 + q * 8];
        gat0 = MFMA(wgf[0][0], hf0, biasg[0], 0, 0, 0);
        gat0 = MFMA(wgf[0][1], hf1, gat0, 0, 0, 0);
        gat0 = MFMA(wgf[0][2], hf2, gat0, 0, 0, 0);
        gat0 = MFMA(wgf[0][3], hf3, gat0, 0, 0, 0);
        gat1 = MFMA(wgf[1][0], hf0, biasg[1], 0, 0, 0);
        gat1 = MFMA(wgf[1][1], hf1, gat1, 0, 0, 0);
        gat1 = MFMA(wgf[1][2], hf2, gat1, 0, 0, 0);
        gat1 = MFMA(wgf[1][3], hf3, gat1, 0, 0, 0);
        #pragma unroll
        for (int r = 0; r < 4; ++r) {
            agg0[r] += hp1_0[r] * hsig(gat0[r]);
            agg1[r] += hp1_1[r] * hsig(gat1[r]);
        }
    }
    const float s = 1.0f / (float)T_SEQ;
    #pragma unroll
    for (int r = 0; r < 4; ++r) { agg0[r] *= s; agg1[r] *= s; }
    *(f32x4*)&agg_out[(long)(b0 + l15) * HID + R0 + q * 4] = agg0;
    *(f32x4*)&agg_out[(long)(b0 + l15) * HID + R1 + q * 4] = agg1;
}

// ---------------- Stage 2a: mapped = agg @ W_map^T + b_map ----------------
template<bool PRE>
__global__ __launch_bounds__(256) void map_kernel(
    const float* __restrict__ agg, const float* __restrict__ Wf,
    const short* __restrict__ Wb, const float* __restrict__ b_map,
    float* __restrict__ mapped)
{
    const int tid  = threadIdx.x;
    const int wave = tid >> 6, lane = tid & 63;
    const int q = lane >> 4, l15 = lane & 15;
    const int mb = blockIdx.x & 31;
    const int nb = blockIdx.x >> 5;
    const int b0 = mb * 16;
    const int n0 = nb * 128 + wave * 32;

    bf16x8 af[4];
    #pragma unroll
    for (int kb = 0; kb < 4; ++kb) {
        const float* p = agg + (b0 + l15) * HID + kb * 32 + q * 8;
        bf16x8 f;
        #pragma unroll
        for (int j = 0; j < 8; ++j) f[j] = f2bf(p[j]);
        af[kb] = f;
    }
    #pragma unroll
    for (int tn = 0; tn < 2; ++tn) {
        int nn = n0 + tn * 16 + l15;
        float bias = b_map[nn];
        f32x4 c;
        #pragma unroll
        for (int r = 0; r < 4; ++r) c[r] = bias;
        #pragma unroll
        for (int kb = 0; kb < 4; ++kb) {
            bf16x8 f;
            if (PRE) {
                f = *(const bf16x8*)(Wb + (long)nn * HID + kb * 32 + q * 8);
            } else {
                const float* p = Wf + (long)nn * HID + kb * 32 + q * 8;
                #pragma unroll
                for (int j = 0; j < 8; ++j) f[j] = f2bf(p[j]);
            }
            c = __builtin_amdgcn_mfma_f32_16x16x32_bf16(af[kb], f, c, 0, 0, 0);
        }
        #pragma unroll
        for (int r = 0; r < 4; ++r)
            mapped[(long)(b0 + q * 4 + r) * 16384 + nn] = c[r];
    }
}

// ---------------- Stage 2b: pool 4x4 -> hardsigmoid -> gate (in place) ----------------
__global__ __launch_bounds__(256) void pool_gate_kernel(float* __restrict__ mapped)
{
    __shared__ float sh_part[256];
    __shared__ float sh_gate[64];
    const int tid = threadIdx.x;
    float* plane = mapped + (long)blockIdx.x * 1024;

    f32x4 m4 = *(const f32x4*)(plane + tid * 4);
    sh_part[tid] = m4[0] + m4[1] + m4[2] + m4[3];
    __syncthreads();
    if (tid < 64) {
        int ph = tid >> 3, pw = tid & 7;
        float s = 0.0f;
        #pragma unroll
        for (int i = 0; i < 4; ++i) s += sh_part[(4 * ph + i) * 8 + pw];
        sh_gate[tid] = hsig(s * (1.0f / 16.0f));
    }
    __syncthreads();
    int h = tid >> 3, wb = tid & 7;
    float g = sh_gate[(h >> 2) * 8 + wb];
    f32x4 o = m4 * g;
    *(f32x4*)(plane + tid * 4) = o;
}

extern "C" void kernel_launch(void* const* d_in, const int* in_sizes, int n_in,
                              void* d_out, int out_size, void* d_ws, size_t ws_size,
                              hipStream_t stream) {
    const float* x      = (const float*)d_in[0];
    const float* W_ih   = (const float*)d_in[1];
    const float* b_ih   = (const float*)d_in[2];
    const float* W_hh   = (const float*)d_in[3];
    const float* b_hh   = (const float*)d_in[4];
    const float* W_gate = (const float*)d_in[5];
    const float* b_gate = (const float*)d_in[6];
    const float* W_map  = (const float*)d_in[7];
    const float* b_map  = (const float*)d_in[8];
    float* out = (float*)d_out;

    const size_t xb_bytes = (size_t)BATCH * T_SEQ * INPUT * 2;
    const size_t wm_bytes = (size_t)16384 * HID * 2;
    const size_t agg_bytes = (size_t)BATCH * HID * 4;
    const bool pre = ws_size >= xb_bytes + wm_bytes + agg_bytes;

    if (pre) {
        short* x_bf  = (short*)d_ws;
        short* wm_bf = (short*)((char*)d_ws + xb_bytes);
        float* agg   = (float*)((char*)d_ws + xb_bytes + wm_bytes);

        cvt_kernel<<<(BATCH * T_SEQ * INPUT / 4 + 255) / 256, 256, 0, stream>>>(x, x_bf, BATCH * T_SEQ * INPUT / 4);
        cvt_kernel<<<(16384 * HID / 4 + 255) / 256, 256, 0, stream>>>(W_map, wm_bf, 16384 * HID / 4);
        rnn_kernel<true><<<32, 256, 0, stream>>>(x, x_bf, W_ih, b_ih, W_hh, b_hh,
                                                 W_gate, b_gate, agg);
        map_kernel<true><<<4096, 256, 0, stream>>>(agg, W_map, wm_bf, b_map, out);
    } else {
        float* agg = (float*)d_ws;
        rnn_kernel<false><<<32, 256, 0, stream>>>(x, nullptr, W_ih, b_ih, W_hh, b_hh,
                                                  W_gate, b_gate, agg);
        map_kernel<false><<<4096, 256, 0, stream>>>(agg, W_map, nullptr, b_map, out);
    }
    pool_gate_kernel<<<BATCH * 16, 256, 0, stream>>>(out);
}

// Round 4
// 707.278 us; speedup vs baseline: 1.0157x; 1.0157x over previous
//
#include <hip/hip_runtime.h>
#include <hip/hip_bf16.h>

#define T_SEQ 1024
#define BATCH 512
#define INPUT 64
#define HID   128

typedef __attribute__((ext_vector_type(8))) short bf16x8;
typedef __attribute__((ext_vector_type(4))) short s16x4;
typedef __attribute__((ext_vector_type(4))) float f32x4;
typedef __attribute__((ext_vector_type(2))) unsigned int u32x2;

#define MFMA __builtin_amdgcn_mfma_f32_16x16x32_bf16

__device__ __forceinline__ short f2bf(float f) {
    union { float f; unsigned u; } v; v.f = f;
    unsigned r = (v.u + 0x7FFFu + ((v.u >> 16) & 1u)) >> 16;
    return (short)r;
}

// packed RNE f32x2 -> bf16x2
__device__ __forceinline__ unsigned cvtpk_bf16(float lo, float hi) {
    unsigned r;
    asm("v_cvt_pk_bf16_f32 %0, %1, %2" : "=v"(r) : "v"(lo), "v"(hi));
    return r;
}

// tanh(x) = 1 - 2/(exp(2x)+1); inf-safe
__device__ __forceinline__ float fast_tanh(float s) {
    float e = __expf(2.0f * s);
    return 1.0f - 2.0f * __builtin_amdgcn_rcpf(e + 1.0f);
}

__device__ __forceinline__ float hsig(float v) {
    return __builtin_amdgcn_fmed3f(v * 0.16666666666666666f + 0.5f, 0.0f, 1.0f);
}

// Barrier draining ONLY lgkmcnt (LDS). Global x-prefetch loads stay in flight.
__device__ __forceinline__ void wg_barrier_lds() {
    asm volatile("s_waitcnt lgkmcnt(0)" ::: "memory");
    __builtin_amdgcn_s_barrier();
    asm volatile("" ::: "memory");
}

// ---------------- prep: f32 -> bf16 bulk convert ----------------
__global__ __launch_bounds__(256) void cvt_kernel(const float* __restrict__ in,
                                                  short* __restrict__ out, int n4) {
    int i = blockIdx.x * 256 + threadIdx.x;
    if (i >= n4) return;
    f32x4 v = ((const f32x4*)in)[i];
    s16x4 o;
    #pragma unroll
    for (int j = 0; j < 4; ++j) o[j] = f2bf(v[j]);
    ((s16x4*)out)[i] = o;
}

// ---------------- Stage 1: recurrence (64 blocks x 8 batches) ----------------
// VALU-issue-bound analysis (R0-R3 all ~1090 cyc/step): per-SIMD element work =
// block_batches*HID/4SIMDs; at 16 batches that's 512 elems -> ~520 VALU cyc/step.
// Fix: 64 blocks x 8 batches (4 waves, 1/SIMD) -> 256 elems/SIMD/step. MFMA cols
// 8-15 compute finite junk (h = tanh => bounded; lanes 8-15 mirror batch l15&7's
// x so no OOB, L1 dedups); stores guarded to l15 < 8.
// Per step: 16 ds_read_b128 (CU), 20 MFMA/wave, agg term for t-1 applied in-step
// (gate(t-1) MFMA result + old hp, before hp overwrite -> no carry registers).
template<bool PRE>
__global__ __launch_bounds__(256) void rnn_kernel(
    const float* __restrict__ xf_, const short* __restrict__ xb,
    const float* __restrict__ W_ih, const float* __restrict__ b_ih,
    const float* __restrict__ W_hh, const float* __restrict__ b_hh,
    const float* __restrict__ W_gate, const float* __restrict__ b_gate,
    float* __restrict__ agg_out)
{
    __shared__ __align__(16) short sh[2][16][136];  // pitch 136 shorts: even bank spread

    const int tid  = threadIdx.x;
    const int wave = tid >> 6, lane = tid & 63;
    const int q = lane >> 4, l15 = lane & 15;
    const int b0 = blockIdx.x * 8;                  // 8 batches per block
    const int xbatch = b0 + (l15 & 7);              // lanes 8-15 mirror 0-7 (no OOB)
    const int R0 = 32 * wave, R1 = R0 + 16;

    // ---- one-time: weight A-frags (lane: W[row = Rt + l15][k = 32f + q*8 + j]) ----
    bf16x8 wih[2][2], whh[2][4], wgf[2][4];
    #pragma unroll
    for (int tile = 0; tile < 2; ++tile) {
        const int row = (tile ? R1 : R0) + l15;
        #pragma unroll
        for (int f = 0; f < 2; ++f) {
            const float* p = W_ih + row * INPUT + f * 32 + q * 8;
            bf16x8 v;
            #pragma unroll
            for (int j = 0; j < 8; ++j) v[j] = f2bf(p[j]);
            wih[tile][f] = v;
        }
        #pragma unroll
        for (int f = 0; f < 4; ++f) {
            const float* p = W_hh + row * HID + f * 32 + q * 8;
            bf16x8 v;
            #pragma unroll
            for (int j = 0; j < 8; ++j) v[j] = f2bf(p[j]);
            whh[tile][f] = v;
        }
        #pragma unroll
        for (int f = 0; f < 4; ++f) {
            const float* p = W_gate + row * HID + f * 32 + q * 8;
            bf16x8 v;
            #pragma unroll
            for (int j = 0; j < 8; ++j) v[j] = f2bf(p[j]);
            wgf[tile][f] = v;
        }
    }

    // ---- biases in C^T layout: row = Rt + q*4 + r ----
    f32x4 bias1[2], biasg[2], zero4;
    #pragma unroll
    for (int tile = 0; tile < 2; ++tile) {
        const int rbase = (tile ? R1 : R0) + q * 4;
        #pragma unroll
        for (int r = 0; r < 4; ++r) {
            bias1[tile][r] = b_ih[rbase + r] + b_hh[rbase + r];
            biasg[tile][r] = b_gate[rbase + r];
        }
    }
    #pragma unroll
    for (int r = 0; r < 4; ++r) zero4[r] = 0.0f;

    f32x4 agg0 = zero4, agg1 = zero4;
    f32x4 hp0 = zero4, hp1 = zero4;       // h(t-1) own values (f32, C^T layout)
    f32x4 axA0, axA1, axB0, axB1;         // accx ping-pong
    bf16x8 xB0a, xB0b, xB1a, xB1b;        // x frag buffers (consumed 2 steps after load)

    const long lanebase = ((long)xbatch * T_SEQ) * INPUT + q * 8;
    const short* xb_lane = PRE ? (xb + lanebase) : nullptr;
    const float* xf_lane = PRE ? nullptr : (xf_ + lanebase);

    auto load_pair = [&](int tt, bf16x8& fa, bf16x8& fb) {
        if constexpr (PRE) {
            const short* p = xb_lane + (long)tt * INPUT;
            fa = *(const bf16x8*)p;
            fb = *(const bf16x8*)(p + 32);
        } else {
            const float* p = xf_lane + (long)tt * INPUT;
            f32x4 a0 = *(const f32x4*)p,        a1 = *(const f32x4*)(p + 4);
            f32x4 a2 = *(const f32x4*)(p + 32), a3 = *(const f32x4*)(p + 36);
            #pragma unroll
            for (int j = 0; j < 4; ++j) {
                fa[j] = f2bf(a0[j]); fa[4 + j] = f2bf(a1[j]);
                fb[j] = f2bf(a2[j]); fb[4 + j] = f2bf(a3[j]);
            }
        }
    };

    // step t: read h(t-1) from sh[(t-1)&1]; accx(t+1) + x refill in ds_read shadow;
    // h(t) MFMAs + gate(t-1) MFMAs; agg(t-1) with OLD hp; commit hp=h(t); write; barrier.
    auto step = [&](int t, f32x4& axM0, f32x4& axM1, f32x4& axS0, f32x4& axS1,
                    bf16x8& xfa, bf16x8& xfb) {
        const int rb = (t & 1) ^ 1, wb = t & 1;
        // 1. issue h(t-1) frag reads
        bf16x8 hf0 = *(const bf16x8*)&sh[rb][l15][q * 8];
        bf16x8 hf1 = *(const bf16x8*)&sh[rb][l15][32 + q * 8];
        bf16x8 hf2 = *(const bf16x8*)&sh[rb][l15][64 + q * 8];
        bf16x8 hf3 = *(const bf16x8*)&sh[rb][l15][96 + q * 8];
        // 2. shadow: accx(t+1) from x(t+1) (loaded 2 steps ago)
        axS0 = MFMA(wih[0][0], xfa, bias1[0], 0, 0, 0);
        axS1 = MFMA(wih[1][0], xfa, bias1[1], 0, 0, 0);
        axS0 = MFMA(wih[0][1], xfb, axS0, 0, 0, 0);
        axS1 = MFMA(wih[1][1], xfb, axS1, 0, 0, 0);
        //    refill this buffer with x(t+3) (clamped; harmless redundant tail loads)
        int tt = t + 3; if (tt > T_SEQ - 1) tt = T_SEQ - 1;
        load_pair(tt, xfa, xfb);
        // 3. h(t) = tanh(W_hh h(t-1) + accx(t)) : 2+2 split for dep latency
        f32x4 a0 = MFMA(whh[0][0], hf0, axM0, 0, 0, 0);
        f32x4 c0 = MFMA(whh[0][2], hf2, zero4, 0, 0, 0);
        f32x4 a1 = MFMA(whh[1][0], hf0, axM1, 0, 0, 0);
        f32x4 c1 = MFMA(whh[1][2], hf2, zero4, 0, 0, 0);
        a0 = MFMA(whh[0][1], hf1, a0, 0, 0, 0);
        c0 = MFMA(whh[0][3], hf3, c0, 0, 0, 0);
        a1 = MFMA(whh[1][1], hf1, a1, 0, 0, 0);
        c1 = MFMA(whh[1][3], hf3, c1, 0, 0, 0);
        // 4. gate(t-1): same frags, 4-chain
        f32x4 g0 = MFMA(wgf[0][0], hf0, biasg[0], 0, 0, 0);
        g0 = MFMA(wgf[0][1], hf1, g0, 0, 0, 0);
        g0 = MFMA(wgf[0][2], hf2, g0, 0, 0, 0);
        g0 = MFMA(wgf[0][3], hf3, g0, 0, 0, 0);
        f32x4 g1 = MFMA(wgf[1][0], hf0, biasg[1], 0, 0, 0);
        g1 = MFMA(wgf[1][1], hf1, g1, 0, 0, 0);
        g1 = MFMA(wgf[1][2], hf2, g1, 0, 0, 0);
        g1 = MFMA(wgf[1][3], hf3, g1, 0, 0, 0);
        // 5. tanh h(t) -> temps (a-results ready first)
        float t00 = fast_tanh(a0[0] + c0[0]);
        float t01 = fast_tanh(a0[1] + c0[1]);
        float t02 = fast_tanh(a0[2] + c0[2]);
        float t03 = fast_tanh(a0[3] + c0[3]);
        float t10 = fast_tanh(a1[0] + c1[0]);
        float t11 = fast_tanh(a1[1] + c1[1]);
        float t12 = fast_tanh(a1[2] + c1[2]);
        float t13 = fast_tanh(a1[3] + c1[3]);
        // 6. agg term for t-1: OLD hp with gate(t-1)
        #pragma unroll
        for (int r = 0; r < 4; ++r) {
            agg0[r] += hp0[r] * hsig(g0[r]);
            agg1[r] += hp1[r] * hsig(g1[r]);
        }
        // 7. commit + pack + write
        hp0[0] = t00; hp0[1] = t01; hp0[2] = t02; hp0[3] = t03;
        hp1[0] = t10; hp1[1] = t11; hp1[2] = t12; hp1[3] = t13;
        u32x2 p0, p1;
        p0[0] = cvtpk_bf16(t00, t01); p0[1] = cvtpk_bf16(t02, t03);
        p1[0] = cvtpk_bf16(t10, t11); p1[1] = cvtpk_bf16(t12, t13);
        *(u32x2*)&sh[wb][l15][R0 + q * 4] = p0;
        *(u32x2*)&sh[wb][l15][R1 + q * 4] = p1;
        wg_barrier_lds();
    };

    // ---- prologue ----
    {
        bf16x8 ta, tb;
        load_pair(0, ta, tb);
        axA0 = MFMA(wih[0][0], ta, bias1[0], 0, 0, 0);
        axA1 = MFMA(wih[1][0], ta, bias1[1], 0, 0, 0);
        axA0 = MFMA(wih[0][1], tb, axA0, 0, 0, 0);
        axA1 = MFMA(wih[1][1], tb, axA1, 0, 0, 0);
        // h(0) = tanh(accx(0))
        hp0[0] = fast_tanh(axA0[0]); hp0[1] = fast_tanh(axA0[1]);
        hp0[2] = fast_tanh(axA0[2]); hp0[3] = fast_tanh(axA0[3]);
        hp1[0] = fast_tanh(axA1[0]); hp1[1] = fast_tanh(axA1[1]);
        hp1[2] = fast_tanh(axA1[2]); hp1[3] = fast_tanh(axA1[3]);
        u32x2 p0, p1;
        p0[0] = cvtpk_bf16(hp0[0], hp0[1]); p0[1] = cvtpk_bf16(hp0[2], hp0[3]);
        p1[0] = cvtpk_bf16(hp1[0], hp1[1]); p1[1] = cvtpk_bf16(hp1[2], hp1[3]);
        *(u32x2*)&sh[0][l15][R0 + q * 4] = p0;
        *(u32x2*)&sh[0][l15][R1 + q * 4] = p1;
        // accx(1)
        load_pair(1, ta, tb);
        axA0 = MFMA(wih[0][0], ta, bias1[0], 0, 0, 0);
        axA1 = MFMA(wih[1][0], ta, bias1[1], 0, 0, 0);
        axA0 = MFMA(wih[0][1], tb, axA0, 0, 0, 0);
        axA1 = MFMA(wih[1][1], tb, axA1, 0, 0, 0);
        // prefetch x(2), x(3)
        load_pair(2, xB0a, xB0b);
        load_pair(3, xB1a, xB1b);
        wg_barrier_lds();
    }

    // ---- main loop: t = 1..1022 in pairs, tail t = 1023 ----
    for (int i = 0; i < 511; ++i) {
        step(2 * i + 1, axA0, axA1, axB0, axB1, xB0a, xB0b);
        step(2 * i + 2, axB0, axB1, axA0, axA1, xB1a, xB1b);
    }
    step(1023, axA0, axA1, axB0, axB1, xB0a, xB0b);

    // ---- epilogue: term for h(1023) (in sh[1]; hp holds h(1023)) ----
    {
        bf16x8 hf0 = *(const bf16x8*)&sh[1][l15][q * 8];
        bf16x8 hf1 = *(const bf16x8*)&sh[1][l15][32 + q * 8];
        bf16x8 hf2 = *(const bf16x8*)&sh[1][l15][64 + q * 8];
        bf16x8 hf3 = *(const bf16x8*)&sh[1][l15][96 + q * 8];
        f32x4 g0 = MFMA(wgf[0][0], hf0, biasg[0], 0, 0, 0);
        g0 = MFMA(wgf[0][1], hf1, g0, 0, 0, 0);
        g0 = MFMA(wgf[0][2], hf2, g0, 0, 0, 0);
        g0 = MFMA(wgf[0][3], hf3, g0, 0, 0, 0);
        f32x4 g1 = MFMA(wgf[1][0], hf0, biasg[1], 0, 0, 0);
        g1 = MFMA(wgf[1][1], hf1, g1, 0, 0, 0);
        g1 = MFMA(wgf[1][2], hf2, g1, 0, 0, 0);
        g1 = MFMA(wgf[1][3], hf3, g1, 0, 0, 0);
        #pragma unroll
        for (int r = 0; r < 4; ++r) {
            agg0[r] += hp0[r] * hsig(g0[r]);
            agg1[r] += hp1[r] * hsig(g1[r]);
        }
    }
    if (l15 < 8) {
        const float s = 1.0f / (float)T_SEQ;
        #pragma unroll
        for (int r = 0; r < 4; ++r) { agg0[r] *= s; agg1[r] *= s; }
        *(f32x4*)&agg_out[(long)(b0 + l15) * HID + R0 + q * 4] = agg0;
        *(f32x4*)&agg_out[(long)(b0 + l15) * HID + R1 + q * 4] = agg1;
    }
}

// ---------------- Stage 2a: mapped = agg @ W_map^T + b_map ----------------
template<bool PRE>
__global__ __launch_bounds__(256) void map_kernel(
    const float* __restrict__ agg, const float* __restrict__ Wf,
    const short* __restrict__ Wb, const float* __restrict__ b_map,
    float* __restrict__ mapped)
{
    const int tid  = threadIdx.x;
    const int wave = tid >> 6, lane = tid & 63;
    const int q = lane >> 4, l15 = lane & 15;
    const int mb = blockIdx.x & 31;
    const int nb = blockIdx.x >> 5;
    const int b0 = mb * 16;
    const int n0 = nb * 128 + wave * 32;

    bf16x8 af[4];
    #pragma unroll
    for (int kb = 0; kb < 4; ++kb) {
        const float* p = agg + (b0 + l15) * HID + kb * 32 + q * 8;
        bf16x8 f;
        #pragma unroll
        for (int j = 0; j < 8; ++j) f[j] = f2bf(p[j]);
        af[kb] = f;
    }
    #pragma unroll
    for (int tn = 0; tn < 2; ++tn) {
        int nn = n0 + tn * 16 + l15;
        float bias = b_map[nn];
        f32x4 c;
        #pragma unroll
        for (int r = 0; r < 4; ++r) c[r] = bias;
        #pragma unroll
        for (int kb = 0; kb < 4; ++kb) {
            bf16x8 f;
            if (PRE) {
                f = *(const bf16x8*)(Wb + (long)nn * HID + kb * 32 + q * 8);
            } else {
                const float* p = Wf + (long)nn * HID + kb * 32 + q * 8;
                #pragma unroll
                for (int j = 0; j < 8; ++j) f[j] = f2bf(p[j]);
            }
            c = __builtin_amdgcn_mfma_f32_16x16x32_bf16(af[kb], f, c, 0, 0, 0);
        }
        #pragma unroll
        for (int r = 0; r < 4; ++r)
            mapped[(long)(b0 + q * 4 + r) * 16384 + nn] = c[r];
    }
}

// ---------------- Stage 2b: pool 4x4 -> hardsigmoid -> gate (in place) ----------------
__global__ __launch_bounds__(256) void pool_gate_kernel(float* __restrict__ mapped)
{
    __shared__ float sh_part[256];
    __shared__ float sh_gate[64];
    const int tid = threadIdx.x;
    float* plane = mapped + (long)blockIdx.x * 1024;

    f32x4 m4 = *(const f32x4*)(plane + tid * 4);
    sh_part[tid] = m4[0] + m4[1] + m4[2] + m4[3];
    __syncthreads();
    if (tid < 64) {
        int ph = tid >> 3, pw = tid & 7;
        float s = 0.0f;
        #pragma unroll
        for (int i = 0; i < 4; ++i) s += sh_part[(4 * ph + i) * 8 + pw];
        sh_gate[tid] = hsig(s * (1.0f / 16.0f));
    }
    __syncthreads();
    int h = tid >> 3, wb = tid & 7;
    float g = sh_gate[(h >> 2) * 8 + wb];
    f32x4 o = m4 * g;
    *(f32x4*)(plane + tid * 4) = o;
}

extern "C" void kernel_launch(void* const* d_in, const int* in_sizes, int n_in,
                              void* d_out, int out_size, void* d_ws, size_t ws_size,
                              hipStream_t stream) {
    const float* x      = (const float*)d_in[0];
    const float* W_ih   = (const float*)d_in[1];
    const float* b_ih   = (const float*)d_in[2];
    const float* W_hh   = (const float*)d_in[3];
    const float* b_hh   = (const float*)d_in[4];
    const float* W_gate = (const float*)d_in[5];
    const float* b_gate = (const float*)d_in[6];
    const float* W_map  = (const float*)d_in[7];
    const float* b_map  = (const float*)d_in[8];
    float* out = (float*)d_out;

    const size_t xb_bytes = (size_t)BATCH * T_SEQ * INPUT * 2;
    const size_t wm_bytes = (size_t)16384 * HID * 2;
    const size_t agg_bytes = (size_t)BATCH * HID * 4;
    const bool pre = ws_size >= xb_bytes + wm_bytes + agg_bytes;

    if (pre) {
        short* x_bf  = (short*)d_ws;
        short* wm_bf = (short*)((char*)d_ws + xb_bytes);
        float* agg   = (float*)((char*)d_ws + xb_bytes + wm_bytes);

        cvt_kernel<<<(BATCH * T_SEQ * INPUT / 4 + 255) / 256, 256, 0, stream>>>(x, x_bf, BATCH * T_SEQ * INPUT / 4);
        cvt_kernel<<<(16384 * HID / 4 + 255) / 256, 256, 0, stream>>>(W_map, wm_bf, 16384 * HID / 4);
        rnn_kernel<true><<<64, 256, 0, stream>>>(x, x_bf, W_ih, b_ih, W_hh, b_hh,
                                                 W_gate, b_gate, agg);
        map_kernel<true><<<4096, 256, 0, stream>>>(agg, W_map, wm_bf, b_map, out);
    } else {
        float* agg = (float*)d_ws;
        rnn_kernel<false><<<64, 256, 0, stream>>>(x, nullptr, W_ih, b_ih, W_hh, b_hh,
                                                  W_gate, b_gate, agg);
        map_kernel<false><<<4096, 256, 0, stream>>>(agg, W_map, nullptr, b_map, out);
    }
    pool_gate_kernel<<<BATCH * 16, 256, 0, stream>>>(out);
}